// Round 1
// baseline (40.044 us; speedup 1.0000x reference)
//
#include <hip/hip_runtime.h>

#define BS 1024
#define D_IN 512
#define D_OUT 512
#define N_MASKS 8
#define NELEM (D_IN * D_OUT)

#define TM 16
#define TN 128
#define BK 32
#define XPAD 2   // XsT stride 18 floats: even (float2-aligned), gcd(18,32)=2 -> conflict-benign

// ---------------- Kernel A: counting sort of rows by state ----------------
// ws[0..8]  = group start offsets (exclusive prefix sum)
// ws[16+p]  = row index at sorted position p (p in [0,1024))
__global__ void __launch_bounds__(BS) sort_kernel(const int* __restrict__ state,
                                                  int* __restrict__ ws) {
    __shared__ int cnt[N_MASKS];
    __shared__ int offs[N_MASKS + 1];
    const int tid = threadIdx.x;
    if (tid < N_MASKS) cnt[tid] = 0;
    __syncthreads();
    const int s = state[tid];
    atomicAdd(&cnt[s], 1);
    __syncthreads();
    if (tid == 0) {
        int acc = 0;
        for (int i = 0; i < N_MASKS; ++i) { offs[i] = acc; acc += cnt[i]; }
        offs[N_MASKS] = acc;
    }
    __syncthreads();
    if (tid <= N_MASKS) ws[tid] = offs[tid];
    if (tid < N_MASKS) cnt[tid] = offs[tid];   // reuse as scatter cursor
    __syncthreads();
    const int pos = atomicAdd(&cnt[s], 1);
    ws[16 + pos] = tid;
}

// ---------------- Kernel B: gathered GEMM per mask group ----------------
// grid = (mask (fastest -> XCD-colocated), col_tile, row_tile_max)
__global__ void __launch_bounds__(256) gemm_kernel(
    const float* __restrict__ x, const float* __restrict__ kern,
    const float* __restrict__ masks, const int* __restrict__ ws,
    float* __restrict__ out)
{
    const int n  = blockIdx.x;            // mask id
    const int n0 = blockIdx.y * TN;       // output-col base
    const int rt = blockIdx.z;            // row tile within group

    const int off0 = ws[n];
    const int off1 = ws[n + 1];
    const int gcnt = off1 - off0;
    if (rt * TM >= gcnt) return;

    __shared__ int   ridx[TM];
    __shared__ float XsT[BK][TM + XPAD];  // transposed X tile: [k][row]
    __shared__ float Wst[BK][TN];         // masked kernel tile: [k][col]

    const int tid = threadIdx.x;
    if (tid < TM) {
        const int p = off0 + rt * TM + tid;
        ridx[tid] = (p < off1) ? ws[16 + p] : -1;
    }
    __syncthreads();

    // staging coords
    const int cW  = tid & 127;            // W col
    const int kbW = tid >> 7;             // 0/1 (k parity)
    const int kkX = tid & 31;             // X k
    // compute coords (also X staging rows)
    const int r0 = (tid >> 5) * 2;        // 2 rows
    const int c0 = (tid & 31) * 4;        // 4 cols

    const int bA = ridx[r0];
    const int bB = ridx[r0 + 1];
    const float* xA = x + (size_t)(bA < 0 ? 0 : bA) * D_IN;  // garbage row ok; store is guarded
    const float* xB = x + (size_t)(bB < 0 ? 0 : bB) * D_IN;
    const float* maskn = masks + (size_t)n * NELEM;

    float acc[2][4] = {{0.f,0.f,0.f,0.f},{0.f,0.f,0.f,0.f}};

    for (int k0 = 0; k0 < D_IN; k0 += BK) {
        __syncthreads();
        // stage X transposed: [k][row]
        XsT[kkX][r0]     = xA[k0 + kkX];
        XsT[kkX][r0 + 1] = xB[k0 + kkX];
        // stage W = kernel * mask : [k][col]
        #pragma unroll
        for (int i = 0; i < 16; ++i) {
            const int kk = kbW + 2 * i;
            const int g  = (k0 + kk) * D_OUT + n0 + cW;
            Wst[kk][cW] = kern[g] * maskn[g];
        }
        __syncthreads();
        #pragma unroll
        for (int kk = 0; kk < BK; ++kk) {
            const float4 w  = *(const float4*)&Wst[kk][c0];
            const float2 xv = *(const float2*)&XsT[kk][r0];
            acc[0][0] += xv.x * w.x; acc[0][1] += xv.x * w.y;
            acc[0][2] += xv.x * w.z; acc[0][3] += xv.x * w.w;
            acc[1][0] += xv.y * w.x; acc[1][1] += xv.y * w.y;
            acc[1][2] += xv.y * w.z; acc[1][3] += xv.y * w.w;
        }
    }

    #pragma unroll
    for (int i = 0; i < 2; ++i) {
        const int b = (i == 0) ? bA : bB;
        if (b < 0) continue;
        float4 o;
        o.x = fmaxf(acc[i][0], 0.f);
        o.y = fmaxf(acc[i][1], 0.f);
        o.z = fmaxf(acc[i][2], 0.f);
        o.w = fmaxf(acc[i][3], 0.f);
        *(float4*)&out[(size_t)b * D_OUT + n0 + c0] = o;
    }
}

extern "C" void kernel_launch(void* const* d_in, const int* in_sizes, int n_in,
                              void* d_out, int out_size, void* d_ws, size_t ws_size,
                              hipStream_t stream) {
    const float* x     = (const float*)d_in[0];
    const int*   state = (const int*)d_in[1];
    const float* kern  = (const float*)d_in[2];
    const float* masks = (const float*)d_in[3];
    float* out = (float*)d_out;
    int*   ws  = (int*)d_ws;

    sort_kernel<<<1, BS, 0, stream>>>(state, ws);
    dim3 grid(N_MASKS, D_OUT / TN, BS / TM);
    gemm_kernel<<<grid, 256, 0, stream>>>(x, kern, masks, ws, out);
}

// Round 2
// 17.874 us; speedup vs baseline: 2.2404x; 2.2404x over previous
//
#include <hip/hip_runtime.h>

#define BS 1024
#define D_IN 512
#define D_OUT 512
#define N_MASKS 8

typedef short bf16x8 __attribute__((ext_vector_type(8)));
typedef float f32x4 __attribute__((ext_vector_type(4)));

// ws layout (bytes):
//   [0,    64)      int group offsets wsi[0..8]
//   [64,   4224)    int row-perm wsi[16 + p], p in [0,1024)
//   [8192, +4MB)    Wf: 8 masks x 16 kb x 32 cb x 1024B fragment blocks
//   [XB_OFF, +1MB)  xb: 1024 x 512 bf16
#define WF_OFF_USH (8192 / 2)
#define WF_USH     (N_MASKS * 16 * 32 * 512)
#define XB_OFF_USH (WF_OFF_USH + WF_USH)

__device__ __forceinline__ ushort f2bf(float f) {
    union { float f; unsigned u; } x; x.f = f;
    unsigned r = (x.u + 0x7fffu + ((x.u >> 16) & 1u)) >> 16;  // RNE
    return (ushort)r;
}

// ---------------- Prepass: pack Wf fragments + xb + sort ----------------
// blocks [0,1024): Wf pack.  [1024,1280): x->bf16.  1280: counting sort.
__global__ void __launch_bounds__(256) prep_kernel(
    const float* __restrict__ x, const int* __restrict__ state,
    const float* __restrict__ kern, const float* __restrict__ masks,
    int* __restrict__ wsi, ushort* __restrict__ wf, ushort* __restrict__ xb)
{
    const int bx  = blockIdx.x;
    const int tid = threadIdx.x;

    if (bx < 1024) {
        // Wf fragment-linear pack: block covers (n, kb, cb0..3), one cb per wave.
        const int n  = bx >> 7;
        const int kb = (bx >> 3) & 15;
        const int cb = (bx & 7) * 4 + (tid >> 6);
        const int l  = tid & 63;
        const int g  = l >> 4;          // k-subgroup
        const int cl = l & 15;          // col within 16
        const int k0  = kb * 32 + g * 8;
        const int col = cb * 16 + cl;
        const float* kp = kern + (size_t)k0 * D_OUT + col;
        const float* mp = masks + (size_t)n * (D_IN * D_OUT) + (size_t)k0 * D_OUT + col;
        uint pk[4];
        #pragma unroll
        for (int j = 0; j < 4; ++j) {
            float v0 = kp[(2*j)   * D_OUT] * mp[(2*j)   * D_OUT];
            float v1 = kp[(2*j+1) * D_OUT] * mp[(2*j+1) * D_OUT];
            pk[j] = (uint)f2bf(v0) | ((uint)f2bf(v1) << 16);
        }
        uint4 o; o.x = pk[0]; o.y = pk[1]; o.z = pk[2]; o.w = pk[3];
        *(uint4*)(wf + ((size_t)((n * 16 + kb) * 32 + cb)) * 512 + l * 8) = o;
    } else if (bx < 1280) {
        // x -> bf16, 8 elements per thread
        const int idx = (bx - 1024) * 256 + tid;        // [0, 65536)
        const float4 a = ((const float4*)x)[idx * 2];
        const float4 b = ((const float4*)x)[idx * 2 + 1];
        uint4 o;
        o.x = (uint)f2bf(a.x) | ((uint)f2bf(a.y) << 16);
        o.y = (uint)f2bf(a.z) | ((uint)f2bf(a.w) << 16);
        o.z = (uint)f2bf(b.x) | ((uint)f2bf(b.y) << 16);
        o.w = (uint)f2bf(b.z) | ((uint)f2bf(b.w) << 16);
        *(uint4*)(xb + (size_t)idx * 8) = o;
    } else {
        // counting sort of 1024 rows by state, 4 rows/thread
        __shared__ int cnt[N_MASKS];
        __shared__ int offs[N_MASKS + 1];
        if (tid < N_MASKS) cnt[tid] = 0;
        __syncthreads();
        int s[4];
        #pragma unroll
        for (int r = 0; r < 4; ++r) {
            s[r] = state[r * 256 + tid];
            atomicAdd(&cnt[s[r]], 1);
        }
        __syncthreads();
        if (tid == 0) {
            int acc = 0;
            for (int i = 0; i < N_MASKS; ++i) { offs[i] = acc; acc += cnt[i]; }
            offs[N_MASKS] = acc;
        }
        __syncthreads();
        if (tid <= N_MASKS) wsi[tid] = offs[tid];
        if (tid < N_MASKS) cnt[tid] = offs[tid];   // scatter cursors
        __syncthreads();
        #pragma unroll
        for (int r = 0; r < 4; ++r) {
            const int pos = atomicAdd(&cnt[s[r]], 1);
            wsi[16 + pos] = r * 256 + tid;
        }
    }
}

// ---------------- GEMM: one wave per 16x32 output tile, MFMA ----------------
// grid = (mask n (fastest -> XCD colocation), colblock of 128, rowtile)
__global__ void __launch_bounds__(256) gemm_kernel(
    const ushort* __restrict__ xb, const ushort* __restrict__ wf,
    const int* __restrict__ wsi, float* __restrict__ out)
{
    const int n     = blockIdx.x;
    const int cb128 = blockIdx.y;
    const int rt    = blockIdx.z;

    const int off0 = wsi[n];
    const int off1 = wsi[n + 1];
    if (rt * 16 >= off1 - off0) return;

    __shared__ int ridx[16];
    const int tid = threadIdx.x;
    if (tid < 16) {
        const int p = off0 + rt * 16 + tid;
        ridx[tid] = (p < off1) ? wsi[16 + p] : -1;
    }
    __syncthreads();

    const int lane = tid & 63;
    const int wid  = tid >> 6;
    const int g    = lane >> 4;     // k subgroup: k = kb*32 + g*8 + j
    const int cl   = lane & 15;

    const int myrow = ridx[cl];     // A row for this lane
    const ushort* xrow = xb + (size_t)(myrow < 0 ? 0 : myrow) * D_IN + g * 8;
    const int cb0 = cb128 * 8 + wid * 2;   // this wave's two 16-col fragments
    const ushort* wp = wf + ((size_t)(n * 16) * 32 + cb0) * 512 + lane * 8;

    f32x4 acc0 = {0.f, 0.f, 0.f, 0.f};
    f32x4 acc1 = {0.f, 0.f, 0.f, 0.f};

    #pragma unroll
    for (int kb = 0; kb < 16; ++kb) {
        const bf16x8 a  = *(const bf16x8*)(xrow + kb * 32);
        const bf16x8 b0 = *(const bf16x8*)(wp + (size_t)kb * 32 * 512);
        const bf16x8 b1 = *(const bf16x8*)(wp + (size_t)kb * 32 * 512 + 512);
        acc0 = __builtin_amdgcn_mfma_f32_16x16x32_bf16(a, b0, acc0, 0, 0, 0);
        acc1 = __builtin_amdgcn_mfma_f32_16x16x32_bf16(a, b1, acc1, 0, 0, 0);
    }

    // C/D: col = lane&15 within fragment, row = g*4 + reg
    #pragma unroll
    for (int r = 0; r < 4; ++r) {
        const int b = ridx[g * 4 + r];
        if (b >= 0) {
            float* op = out + (size_t)b * D_OUT;
            op[cb0 * 16 + cl]       = fmaxf(acc0[r], 0.f);
            op[(cb0 + 1) * 16 + cl] = fmaxf(acc1[r], 0.f);
        }
    }
}

extern "C" void kernel_launch(void* const* d_in, const int* in_sizes, int n_in,
                              void* d_out, int out_size, void* d_ws, size_t ws_size,
                              hipStream_t stream) {
    const float* x     = (const float*)d_in[0];
    const int*   state = (const int*)d_in[1];
    const float* kern  = (const float*)d_in[2];
    const float* masks = (const float*)d_in[3];
    float*  out = (float*)d_out;
    int*    wsi = (int*)d_ws;
    ushort* wsu = (ushort*)d_ws;

    prep_kernel<<<1281, 256, 0, stream>>>(x, state, kern, masks,
                                          wsi, wsu + WF_OFF_USH, wsu + XB_OFF_USH);
    dim3 grid(N_MASKS, D_OUT / 128, BS / 16);
    gemm_kernel<<<grid, 256, 0, stream>>>(wsu + XB_OFF_USH, wsu + WF_OFF_USH, wsi, out);
}